// Round 2
// baseline (625.768 us; speedup 1.0000x reference)
//
#include <hip/hip_runtime.h>
#include <stdint.h>

// ---------------------------------------------------------------------------
// CommonFeatureExtractor on MI355X.
// Pipeline:
//   cvt3:        3x [16384,1024] f32 -> bf16              (XB)
//   transpose:   weights f32 [K][N] -> bf16 [Npad][Kpad] (B^T layout, zero pad)
//   GEMM1 (x3 via grid.z): Y = relu(X @ W1 + b1)        -> bf16 [16384,384] (YB, in d_out)
//   GEMM2 (x3 via grid.z): E = Y @ W2 + b2              -> bf16 [16384,1024] (EB = XB region)
//   pointwise:   norms/sim/keep/softmax/wg-gate         -> common (COM, in d_out), wfs -> FA left
//   GEMM enh:    FA[:,1024:] = common * sigmoid(common @ enhW + enhb)
//   GEMM fused:  out = FA @ fusW + fusb                 -> f32 (d_out)
// Buffer lifetime aliasing keeps d_ws usage to ~170 MB:
//   ws:    [XB/EB 96MB][FA 64MB][bf16 weights ~10MB]
//   d_out: YB (GEMM1->GEMM2), then COM (PW->enh), then final output.
// GEMM: m97 recipe — 128x128 tile, 4 waves, 16x16x32 bf16 MFMA,
//       global_load_lds width=16 staging.
// ---------------------------------------------------------------------------

typedef __attribute__((ext_vector_type(8))) __bf16 bf16x8;
typedef __attribute__((ext_vector_type(8))) short short8;
typedef __attribute__((ext_vector_type(4))) float floatx4;

__device__ __forceinline__ uint16_t f2bf(float f) {
  union { float f; uint32_t u; } v; v.f = f;
  uint32_t r = v.u + 0x7fffu + ((v.u >> 16) & 1u);  // round-to-nearest-even
  return (uint16_t)(r >> 16);
}
__device__ __forceinline__ float bf2f(uint16_t h) {
  union { uint32_t u; float f; } v; v.u = ((uint32_t)h) << 16;
  return v.f;
}
__device__ __forceinline__ void gload16(const void* g, void* l) {
  __builtin_amdgcn_global_load_lds(
      (const __attribute__((address_space(1))) void*)g,
      (__attribute__((address_space(3))) void*)l, 16, 0, 0);
}

// --------------------------- fp32 -> bf16 convert --------------------------
__global__ void cfe_cvt3_kernel(const float* __restrict__ s0,
                                const float* __restrict__ s1,
                                const float* __restrict__ s2,
                                uint16_t* __restrict__ dst) {
  const float* s = (blockIdx.y == 0) ? s0 : ((blockIdx.y == 1) ? s1 : s2);
  long i = (long)blockIdx.x * 256 + threadIdx.x;  // group of 4 floats
  float4 v = ((const float4*)s)[i];
  ushort4 o;
  o.x = f2bf(v.x); o.y = f2bf(v.y); o.z = f2bf(v.z); o.w = f2bf(v.w);
  ((ushort4*)dst)[(long)blockIdx.y * (16384L * 1024 / 4) + i] = o;
}

// ----------------- transpose + convert: dst[n][k] = src[k][n] ---------------
__global__ void cfe_transpose_cvt_kernel(const float* __restrict__ src,
                                         uint16_t* __restrict__ dst,
                                         int K, int N, int Kpad, int Npad) {
  __shared__ float tile[32][33];
  const int tx = threadIdx.x & 31;
  const int ty = threadIdx.x >> 5;  // 0..7
  const int k0 = blockIdx.x * 32;
  const int n0 = blockIdx.y * 32;
#pragma unroll
  for (int i = 0; i < 4; i++) {
    int k = k0 + ty + 8 * i;
    int n = n0 + tx;
    tile[ty + 8 * i][tx] = (k < K && n < N) ? src[(long)k * N + n] : 0.f;
  }
  __syncthreads();
#pragma unroll
  for (int i = 0; i < 4; i++) {
    int n = n0 + ty + 8 * i;
    int k = k0 + tx;
    if (n < Npad && k < Kpad) dst[(long)n * Kpad + k] = f2bf(tile[tx][ty + 8 * i]);
  }
}

// ------------------------------- GEMM 128x128 -------------------------------
// A [M][lda] bf16 row-major, Bt [N][ldb] bf16 (B transposed), C per MODE.
// MODE 0: bias+relu -> bf16 ; MODE 1: bias -> bf16 ;
// MODE 2: sigmoid(acc+bias)*common -> bf16 at col offset ; MODE 3: bias -> f32
template <int MODE>
__global__ void cfe_gemm128(const uint16_t* __restrict__ A, long sAz, int lda,
                            const uint16_t* __restrict__ Bt, long sBz, int ldb,
                            void* __restrict__ C, long sCz, int ldc, int colofs,
                            const float* __restrict__ bias0,
                            const float* __restrict__ bias1,
                            const float* __restrict__ bias2, int biasN,
                            const uint16_t* __restrict__ common, int K) {
  const int z = blockIdx.z;
  A += (long)z * sAz;
  Bt += (long)z * sBz;
  const float* bias = (z == 0) ? bias0 : ((z == 1) ? bias1 : bias2);

  const int tid = threadIdx.x;
  const int wave = tid >> 6;
  const int lane = tid & 63;
  const int wm = wave >> 1;  // 0..1
  const int wn = wave & 1;
  const long bm = (long)blockIdx.y * 128;
  const long bn = (long)blockIdx.x * 128;

  __shared__ __attribute__((aligned(16))) uint16_t As[128 * 32];
  __shared__ __attribute__((aligned(16))) uint16_t Bs[128 * 32];

  floatx4 acc[4][4];
#pragma unroll
  for (int i = 0; i < 4; i++)
#pragma unroll
    for (int j = 0; j < 4; j++) acc[i][j] = (floatx4){0.f, 0.f, 0.f, 0.f};

  // staging: each wave fills 32 rows of As/Bs; one issue = 16 rows (4 lanes/row)
  const int lrow = lane >> 2;
  const int lcol = (lane & 3) * 8;
  const uint16_t* Ap = A + (bm + wave * 32 + lrow) * (long)lda + lcol;
  const uint16_t* Bp = Bt + (bn + wave * 32 + lrow) * (long)ldb + lcol;
  uint16_t* AsW0 = &As[(wave * 32) * 32];
  uint16_t* AsW1 = &As[(wave * 32 + 16) * 32];
  uint16_t* BsW0 = &Bs[(wave * 32) * 32];
  uint16_t* BsW1 = &Bs[(wave * 32 + 16) * 32];

  const int fr = lane & 15;
  const int fq = lane >> 4;  // 0..3
  const uint16_t* ArBase = &As[(wm * 64 + fr) * 32 + fq * 8];
  const uint16_t* BrBase = &Bs[(wn * 64 + fr) * 32 + fq * 8];

  for (int k0 = 0; k0 < K; k0 += 32) {
    gload16(Ap + k0, AsW0);
    gload16(Ap + 16 * (long)lda + k0, AsW1);
    gload16(Bp + k0, BsW0);
    gload16(Bp + 16 * (long)ldb + k0, BsW1);
    __syncthreads();

    short8 a[4], b[4];
#pragma unroll
    for (int mi = 0; mi < 4; mi++) a[mi] = *(const short8*)(ArBase + mi * 16 * 32);
#pragma unroll
    for (int ni = 0; ni < 4; ni++) b[ni] = *(const short8*)(BrBase + ni * 16 * 32);
#pragma unroll
    for (int mi = 0; mi < 4; mi++)
#pragma unroll
      for (int ni = 0; ni < 4; ni++)
        acc[mi][ni] = __builtin_amdgcn_mfma_f32_16x16x32_bf16(
            __builtin_bit_cast(bf16x8, a[mi]), __builtin_bit_cast(bf16x8, b[ni]),
            acc[mi][ni], 0, 0, 0);
    __syncthreads();
  }

  // epilogue: D[row=fq*4+r][col=fr] per 16x16 tile
#pragma unroll
  for (int mi = 0; mi < 4; mi++) {
    long row = bm + wm * 64 + mi * 16 + fq * 4;
#pragma unroll
    for (int ni = 0; ni < 4; ni++) {
      long col = bn + wn * 64 + ni * 16 + fr;
      float bv = (col < biasN) ? bias[col] : 0.f;
#pragma unroll
      for (int r = 0; r < 4; r++) {
        float v = acc[mi][ni][r] + bv;
        long idx = (row + r) * (long)ldc + colofs + col;
        if constexpr (MODE == 0) {
          ((uint16_t*)C)[(long)z * sCz + idx] = f2bf(fmaxf(v, 0.f));
        } else if constexpr (MODE == 1) {
          ((uint16_t*)C)[(long)z * sCz + idx] = f2bf(v);
        } else if constexpr (MODE == 2) {
          float c = bf2f(common[(row + r) * 1024 + col]);
          float s = 1.f / (1.f + __expf(-v));
          ((uint16_t*)C)[idx] = f2bf(c * s);
        } else {
          ((float*)C)[idx] = v;
        }
      }
    }
  }
}

// ------------------------------- pointwise ---------------------------------
// One block per row. E = [eb|ef|ep] bf16, each 16384x1024, contiguous.
__global__ void cfe_pointwise_kernel(const uint16_t* __restrict__ E,
                                     const float* __restrict__ wgW,
                                     const float* __restrict__ wgb,
                                     uint16_t* __restrict__ commonb,
                                     uint16_t* __restrict__ fusedA) {
  const int row = blockIdx.x;
  const int tid = threadIdx.x;
  const long ES = 16384L * 1024;
  const long base = (long)row * 1024 + tid * 4;

  ushort4 u0 = *(const ushort4*)(E + base);
  ushort4 u1 = *(const ushort4*)(E + ES + base);
  ushort4 u2 = *(const ushort4*)(E + 2 * ES + base);
  float eb[4] = {bf2f(u0.x), bf2f(u0.y), bf2f(u0.z), bf2f(u0.w)};
  float ef[4] = {bf2f(u1.x), bf2f(u1.y), bf2f(u1.z), bf2f(u1.w)};
  float ep[4] = {bf2f(u2.x), bf2f(u2.y), bf2f(u2.z), bf2f(u2.w)};

  float vals[9];
#pragma unroll
  for (int i = 0; i < 9; i++) vals[i] = 0.f;
#pragma unroll
  for (int j = 0; j < 4; j++) {
    int h = tid * 4 + j;
    vals[0] += eb[j] * eb[j];
    vals[1] += ef[j] * ef[j];
    vals[2] += ep[j] * ep[j];
    vals[3] += eb[j] * ef[j];
    vals[4] += eb[j] * ep[j];
    vals[5] += ef[j] * ep[j];
#pragma unroll
    for (int c = 0; c < 3; c++)
      vals[6 + c] += eb[j] * wgW[(long)h * 3 + c] +
                     ef[j] * wgW[(long)(1024 + h) * 3 + c] +
                     ep[j] * wgW[(long)(2048 + h) * 3 + c];
  }

#pragma unroll
  for (int i = 0; i < 9; i++) {
    float v = vals[i];
    for (int off = 32; off; off >>= 1) v += __shfl_down(v, off);
    vals[i] = v;
  }
  __shared__ float red[4][9];
  if ((tid & 63) == 0) {
#pragma unroll
    for (int i = 0; i < 9; i++) red[tid >> 6][i] = vals[i];
  }
  __syncthreads();
  float tot[9];
#pragma unroll
  for (int i = 0; i < 9; i++)
    tot[i] = red[0][i] + red[1][i] + red[2][i] + red[3][i];

  const float EPSF = 1e-12f;
  float nb = fmaxf(sqrtf(tot[0]), EPSF);
  float nf = fmaxf(sqrtf(tot[1]), EPSF);
  float np_ = fmaxf(sqrtf(tot[2]), EPSF);
  float s01 = tot[3] / (nb * nf);
  float s02 = tot[4] / (nb * np_);
  float s12 = tot[5] / (nf * np_);
  bool k01 = s01 > 0.6f, k02 = s02 > 0.6f, k12 = s12 > 0.6f;
  bool any = k01 | k02 | k12;
  float z0 = k01 ? s01 : -1e9f;
  float z1 = k02 ? s02 : -1e9f;
  float z2 = k12 ? s12 : -1e9f;
  float zm = fmaxf(z0, fmaxf(z1, z2));
  float w0 = __expf(z0 - zm), w1 = __expf(z1 - zm), w2 = __expf(z2 - zm);
  float wsum = w0 + w1 + w2;
  w0 /= wsum; w1 /= wsum; w2 /= wsum;

  float g0 = tot[6] + wgb[0], g1 = tot[7] + wgb[1], g2 = tot[8] + wgb[2];
  float gm = fmaxf(g0, fmaxf(g1, g2));
  float f0 = __expf(g0 - gm), f1 = __expf(g1 - gm), f2 = __expf(g2 - gm);
  float fs = f0 + f1 + f2;
  f0 /= fs; f1 /= fs; f2 /= fs;

  float inb = 1.f / nb, inf_ = 1.f / nf, inp = 1.f / np_;
  ushort4 co, wf;
  uint16_t cov[4], wfv[4];
#pragma unroll
  for (int j = 0; j < 4; j++) {
    float b = eb[j], f = ef[j], p = ep[j];
    float nbv = b * inb, nfv = f * inf_, npv = p * inp;
    float c01 = (nbv * nfv > 0.6f) ? 0.5f * (b + f) : 0.f;
    float c02 = (nbv * npv > 0.6f) ? 0.5f * (b + p) : 0.f;
    float c12 = (nfv * npv > 0.6f) ? 0.5f * (f + p) : 0.f;
    float ws = w0 * c01 + w1 * c02 + w2 * c12;
    float cm = any ? ws : (b + f + p) * (1.f / 3.f);
    float wfs = f0 * b + f1 * f + f2 * p;
    cov[j] = f2bf(cm);
    wfv[j] = f2bf(wfs);
  }
  co.x = cov[0]; co.y = cov[1]; co.z = cov[2]; co.w = cov[3];
  wf.x = wfv[0]; wf.y = wfv[1]; wf.z = wfv[2]; wf.w = wfv[3];
  *(ushort4*)(commonb + base) = co;
  *(ushort4*)(fusedA + (long)row * 2048 + tid * 4) = wf;
}

// ------------------------------- launcher ----------------------------------
extern "C" void kernel_launch(void* const* d_in, const int* in_sizes, int n_in,
                              void* d_out, int out_size, void* d_ws, size_t ws_size,
                              hipStream_t stream) {
  (void)in_sizes; (void)n_in; (void)out_size; (void)ws_size;
  const float* brics = (const float*)d_in[0];
  const float* fg    = (const float*)d_in[1];
  const float* ph    = (const float*)d_in[2];
  const float* bw1 = (const float*)d_in[3];  const float* bb1 = (const float*)d_in[4];
  const float* bw2 = (const float*)d_in[5];  const float* bb2 = (const float*)d_in[6];
  const float* fw1 = (const float*)d_in[7];  const float* fb1 = (const float*)d_in[8];
  const float* fw2 = (const float*)d_in[9];  const float* fb2 = (const float*)d_in[10];
  const float* pw1 = (const float*)d_in[11]; const float* pb1 = (const float*)d_in[12];
  const float* pw2 = (const float*)d_in[13]; const float* pb2 = (const float*)d_in[14];
  const float* wgW = (const float*)d_in[15]; const float* wgb = (const float*)d_in[16];
  const float* enhW = (const float*)d_in[17]; const float* enhb = (const float*)d_in[18];
  const float* fusW = (const float*)d_in[19]; const float* fusb = (const float*)d_in[20];
  float* out = (float*)d_out;

  // ws layout (~170 MB): [XB/EB 96MB][FA 64MB][weights ~10MB]
  uint16_t* XB   = (uint16_t*)d_ws;            // 3 * 16384*1024 bf16 (later EB)
  uint16_t* EB   = XB;                         // aliases XB (X dead after GEMM1)
  uint16_t* FA   = XB + 3L * 16384 * 1024;     // 16384*2048
  uint16_t* W1T  = FA + 16384L * 2048;         // 3 * 384*1024
  uint16_t* W2T  = W1T + 3L * 384 * 1024;      // 3 * 1024*320
  uint16_t* ENHT = W2T + 3L * 1024 * 320;      // 1024*1024
  uint16_t* FUST = ENHT + 1024L * 1024;        // 1024*2048
  // d_out doubles as scratch before the final GEMM overwrites it:
  uint16_t* YB   = (uint16_t*)d_out;           // 3 * 16384*384 (36MB <= 64MB)
  uint16_t* COM  = (uint16_t*)d_out;           // 16384*1024 (32MB; after YB dead)

  // input conversions
  cfe_cvt3_kernel<<<dim3(16384, 3), 256, 0, stream>>>(brics, fg, ph, XB);

  // weight transposes (f32 [K][N] -> bf16 [Npad][Kpad], zero-padded)
  cfe_transpose_cvt_kernel<<<dim3(32, 12), 256, 0, stream>>>(bw1, W1T + 0L * 384 * 1024, 1024, 300, 1024, 384);
  cfe_transpose_cvt_kernel<<<dim3(32, 12), 256, 0, stream>>>(fw1, W1T + 1L * 384 * 1024, 1024, 300, 1024, 384);
  cfe_transpose_cvt_kernel<<<dim3(32, 12), 256, 0, stream>>>(pw1, W1T + 2L * 384 * 1024, 1024, 300, 1024, 384);
  cfe_transpose_cvt_kernel<<<dim3(10, 32), 256, 0, stream>>>(bw2, W2T + 0L * 1024 * 320, 300, 1024, 320, 1024);
  cfe_transpose_cvt_kernel<<<dim3(10, 32), 256, 0, stream>>>(fw2, W2T + 1L * 1024 * 320, 300, 1024, 320, 1024);
  cfe_transpose_cvt_kernel<<<dim3(10, 32), 256, 0, stream>>>(pw2, W2T + 2L * 1024 * 320, 300, 1024, 320, 1024);
  cfe_transpose_cvt_kernel<<<dim3(32, 32), 256, 0, stream>>>(enhW, ENHT, 1024, 1024, 1024, 1024);
  cfe_transpose_cvt_kernel<<<dim3(64, 32), 256, 0, stream>>>(fusW, FUST, 2048, 1024, 2048, 1024);

  // GEMM1: Y = relu(X @ W1 + b1)   M=16384 N=384 K=1024
  cfe_gemm128<0><<<dim3(3, 128, 3), 256, 0, stream>>>(
      XB, 16384L * 1024, 1024, W1T, 384L * 1024, 1024,
      YB, 16384L * 384, 384, 0, bb1, fb1, pb1, 300, nullptr, 1024);

  // GEMM2: E = Y @ W2 + b2         M=16384 N=1024 K=320  (writes EB = XB region)
  cfe_gemm128<1><<<dim3(8, 128, 3), 256, 0, stream>>>(
      YB, 16384L * 384, 384, W2T, 1024L * 320, 320,
      EB, 16384L * 1024, 1024, 0, bb2, fb2, pb2, 1024, nullptr, 320);

  // pointwise: common (-> d_out region) + weighted_fp_sum (-> FA left half)
  cfe_pointwise_kernel<<<16384, 256, 0, stream>>>(EB, wgW, wgb, COM, FA);

  // enh: FA[:,1024:] = common * sigmoid(common @ enhW + enhb)
  cfe_gemm128<2><<<dim3(8, 128, 1), 256, 0, stream>>>(
      COM, 0, 1024, ENHT, 0, 1024,
      FA, 0, 2048, 1024, enhb, enhb, enhb, 1024, COM, 1024);

  // fused: out = FA @ fusW + fusb   M=16384 N=1024 K=2048
  cfe_gemm128<3><<<dim3(8, 128, 1), 256, 0, stream>>>(
      FA, 0, 2048, FUST, 0, 2048,
      out, 0, 1024, 0, fusb, fusb, fusb, 1024, nullptr, 2048);
}

// Round 3
// 568.828 us; speedup vs baseline: 1.1001x; 1.1001x over previous
//
#include <hip/hip_runtime.h>
#include <stdint.h>

// ---------------------------------------------------------------------------
// CommonFeatureExtractor on MI355X.  Round 3.
// Changes vs round 2:
//  - cvt3 pass removed: GEMM1 (MODE 0) reads f32 inputs directly (AF32 path:
//    float4 loads -> bf16 pack -> ds_write_b128).  Saves 288 MB HBM pass.
//  - XCD-aware block swizzle in all GEMMs: v=(lin%8)*(T/8)+lin/8 groups
//    blocks sharing an A-strip onto one XCD (round-robin inversion) so the
//    strip + full B stay hot in that XCD's 4 MB L2.  Target: fused-GEMM
//    FETCH_SIZE 266 MB -> ~120 MB.  Requires gridX*gridY % 8 == 0 (all true).
//  - transposes batched 8 -> 4 launches via grid.z.
// Buffers: ws = [EB 96MB][FA 64MB][bf16 weights ~10MB]; d_out hosts YB then
// COM before the final GEMM overwrites it.
// ---------------------------------------------------------------------------

typedef __attribute__((ext_vector_type(8))) __bf16 bf16x8;
typedef __attribute__((ext_vector_type(8))) short short8;
typedef __attribute__((ext_vector_type(4))) float floatx4;

__device__ __forceinline__ uint16_t f2bf(float f) {
  union { float f; uint32_t u; } v; v.f = f;
  uint32_t r = v.u + 0x7fffu + ((v.u >> 16) & 1u);  // round-to-nearest-even
  return (uint16_t)(r >> 16);
}
__device__ __forceinline__ float bf2f(uint16_t h) {
  union { uint32_t u; float f; } v; v.u = ((uint32_t)h) << 16;
  return v.f;
}
__device__ __forceinline__ void gload16(const void* g, void* l) {
  __builtin_amdgcn_global_load_lds(
      (const __attribute__((address_space(1))) void*)g,
      (__attribute__((address_space(3))) void*)l, 16, 0, 0);
}

// ----------- batched transpose + convert: dst[z][n][k] = src_z[k][n] --------
__global__ void cfe_transpose3_cvt_kernel(const float* __restrict__ s0,
                                          const float* __restrict__ s1,
                                          const float* __restrict__ s2,
                                          uint16_t* __restrict__ dst, long dstStride,
                                          int K, int N, int Kpad, int Npad) {
  const float* src = (blockIdx.z == 0) ? s0 : ((blockIdx.z == 1) ? s1 : s2);
  uint16_t* d = dst + (long)blockIdx.z * dstStride;
  __shared__ float tile[32][33];
  const int tx = threadIdx.x & 31;
  const int ty = threadIdx.x >> 5;  // 0..7
  const int k0 = blockIdx.x * 32;
  const int n0 = blockIdx.y * 32;
#pragma unroll
  for (int i = 0; i < 4; i++) {
    int k = k0 + ty + 8 * i;
    int n = n0 + tx;
    tile[ty + 8 * i][tx] = (k < K && n < N) ? src[(long)k * N + n] : 0.f;
  }
  __syncthreads();
#pragma unroll
  for (int i = 0; i < 4; i++) {
    int n = n0 + ty + 8 * i;
    int k = k0 + tx;
    if (n < Npad && k < Kpad) d[(long)n * Kpad + k] = f2bf(tile[tx][ty + 8 * i]);
  }
}

// ------------------------------- GEMM 128x128 -------------------------------
// A (z-select among A0/A1/A2): bf16 [M][lda], or f32 when AF32=1.
// Bt [N][ldb] bf16 (B transposed, z via sBz).  C per MODE.
// MODE 0: bias+relu -> bf16 ; MODE 1: bias -> bf16 ;
// MODE 2: sigmoid(acc+bias)*common -> bf16 at col offset ; MODE 3: bias -> f32
template <int MODE, int AF32>
__global__ void cfe_gemm128(const void* __restrict__ A0, const void* __restrict__ A1,
                            const void* __restrict__ A2, int lda,
                            const uint16_t* __restrict__ Bt, long sBz, int ldb,
                            void* __restrict__ C, long sCz, int ldc, int colofs,
                            const float* __restrict__ bias0,
                            const float* __restrict__ bias1,
                            const float* __restrict__ bias2, int biasN,
                            const uint16_t* __restrict__ common, int K) {
  const int z = blockIdx.z;
  const void* Av = (z == 0) ? A0 : ((z == 1) ? A1 : A2);
  Bt += (long)z * sBz;
  const float* bias = (z == 0) ? bias0 : ((z == 1) ? bias1 : bias2);

  // XCD-aware swizzle: invert round-robin so blocks sharing an A-strip (same
  // bm, all bn) are contiguous on one XCD.  Requires gx*gy % 8 == 0.
  const int gx = gridDim.x;
  const int lin = blockIdx.y * gx + blockIdx.x;
  const int P = (gx * gridDim.y) >> 3;
  const int v = (lin & 7) * P + (lin >> 3);
  const long bm = (long)(v / gx) * 128;
  const long bn = (long)(v % gx) * 128;

  const int tid = threadIdx.x;
  const int wave = tid >> 6;
  const int lane = tid & 63;
  const int wm = wave >> 1;  // 0..1
  const int wn = wave & 1;

  __shared__ __attribute__((aligned(16))) uint16_t As[128 * 32];
  __shared__ __attribute__((aligned(16))) uint16_t Bs[128 * 32];

  floatx4 acc[4][4];
#pragma unroll
  for (int i = 0; i < 4; i++)
#pragma unroll
    for (int j = 0; j < 4; j++) acc[i][j] = (floatx4){0.f, 0.f, 0.f, 0.f};

  // staging: each wave fills 32 rows of As/Bs; one issue = 16 rows (4 lanes/row)
  const int lrow = lane >> 2;
  const int lcol = (lane & 3) * 8;  // in elements (8 elems per lane)
  const uint16_t* Bp = Bt + (bn + wave * 32 + lrow) * (long)ldb + lcol;
  uint16_t* BsW0 = &Bs[(wave * 32) * 32];
  uint16_t* BsW1 = &Bs[(wave * 32 + 16) * 32];
  // bf16-A path pointers
  const uint16_t* Ap = nullptr;
  uint16_t* AsW0 = &As[(wave * 32) * 32];
  uint16_t* AsW1 = &As[(wave * 32 + 16) * 32];
  // f32-A path pointers
  const float* ApF0 = nullptr;
  const float* ApF1 = nullptr;
  short8* AsF0 = (short8*)&As[(wave * 32 + lrow) * 32 + lcol];
  short8* AsF1 = (short8*)&As[(wave * 32 + 16 + lrow) * 32 + lcol];
  if constexpr (AF32) {
    ApF0 = (const float*)Av + (bm + wave * 32 + lrow) * (long)lda + lcol;
    ApF1 = ApF0 + 16 * (long)lda;
  } else {
    Ap = (const uint16_t*)Av + (bm + wave * 32 + lrow) * (long)lda + lcol;
  }

  const int fr = lane & 15;
  const int fq = lane >> 4;  // 0..3
  const uint16_t* ArBase = &As[(wm * 64 + fr) * 32 + fq * 8];
  const uint16_t* BrBase = &Bs[(wn * 64 + fr) * 32 + fq * 8];

  for (int k0 = 0; k0 < K; k0 += 32) {
    if constexpr (AF32) {
      float4 f0 = *(const float4*)(ApF0 + k0);
      float4 f1 = *(const float4*)(ApF0 + k0 + 4);
      float4 f2 = *(const float4*)(ApF1 + k0);
      float4 f3 = *(const float4*)(ApF1 + k0 + 4);
      gload16(Bp + k0, BsW0);
      gload16(Bp + 16 * (long)ldb + k0, BsW1);
      union { uint16_t u[8]; short8 s; } p0, p1;
      p0.u[0] = f2bf(f0.x); p0.u[1] = f2bf(f0.y); p0.u[2] = f2bf(f0.z); p0.u[3] = f2bf(f0.w);
      p0.u[4] = f2bf(f1.x); p0.u[5] = f2bf(f1.y); p0.u[6] = f2bf(f1.z); p0.u[7] = f2bf(f1.w);
      p1.u[0] = f2bf(f2.x); p1.u[1] = f2bf(f2.y); p1.u[2] = f2bf(f2.z); p1.u[3] = f2bf(f2.w);
      p1.u[4] = f2bf(f3.x); p1.u[5] = f2bf(f3.y); p1.u[6] = f2bf(f3.z); p1.u[7] = f2bf(f3.w);
      *AsF0 = p0.s;
      *AsF1 = p1.s;
    } else {
      gload16(Ap + k0, AsW0);
      gload16(Ap + 16 * (long)lda + k0, AsW1);
      gload16(Bp + k0, BsW0);
      gload16(Bp + 16 * (long)ldb + k0, BsW1);
    }
    __syncthreads();

    short8 a[4], b[4];
#pragma unroll
    for (int mi = 0; mi < 4; mi++) a[mi] = *(const short8*)(ArBase + mi * 16 * 32);
#pragma unroll
    for (int ni = 0; ni < 4; ni++) b[ni] = *(const short8*)(BrBase + ni * 16 * 32);
#pragma unroll
    for (int mi = 0; mi < 4; mi++)
#pragma unroll
      for (int ni = 0; ni < 4; ni++)
        acc[mi][ni] = __builtin_amdgcn_mfma_f32_16x16x32_bf16(
            __builtin_bit_cast(bf16x8, a[mi]), __builtin_bit_cast(bf16x8, b[ni]),
            acc[mi][ni], 0, 0, 0);
    __syncthreads();
  }

  // epilogue: D[row=fq*4+r][col=fr] per 16x16 tile
#pragma unroll
  for (int mi = 0; mi < 4; mi++) {
    long row = bm + wm * 64 + mi * 16 + fq * 4;
#pragma unroll
    for (int ni = 0; ni < 4; ni++) {
      long col = bn + wn * 64 + ni * 16 + fr;
      float bv = (col < biasN) ? bias[col] : 0.f;
#pragma unroll
      for (int r = 0; r < 4; r++) {
        float vv = acc[mi][ni][r] + bv;
        long idx = (row + r) * (long)ldc + colofs + col;
        if constexpr (MODE == 0) {
          ((uint16_t*)C)[(long)z * sCz + idx] = f2bf(fmaxf(vv, 0.f));
        } else if constexpr (MODE == 1) {
          ((uint16_t*)C)[(long)z * sCz + idx] = f2bf(vv);
        } else if constexpr (MODE == 2) {
          float c = bf2f(common[(row + r) * 1024 + col]);
          float s = 1.f / (1.f + __expf(-vv));
          ((uint16_t*)C)[idx] = f2bf(c * s);
        } else {
          ((float*)C)[idx] = vv;
        }
      }
    }
  }
}

// ------------------------------- pointwise ---------------------------------
// One block per row. E = [eb|ef|ep] bf16, each 16384x1024, contiguous.
__global__ void cfe_pointwise_kernel(const uint16_t* __restrict__ E,
                                     const float* __restrict__ wgW,
                                     const float* __restrict__ wgb,
                                     uint16_t* __restrict__ commonb,
                                     uint16_t* __restrict__ fusedA) {
  const int row = blockIdx.x;
  const int tid = threadIdx.x;
  const long ES = 16384L * 1024;
  const long base = (long)row * 1024 + tid * 4;

  ushort4 u0 = *(const ushort4*)(E + base);
  ushort4 u1 = *(const ushort4*)(E + ES + base);
  ushort4 u2 = *(const ushort4*)(E + 2 * ES + base);
  float eb[4] = {bf2f(u0.x), bf2f(u0.y), bf2f(u0.z), bf2f(u0.w)};
  float ef[4] = {bf2f(u1.x), bf2f(u1.y), bf2f(u1.z), bf2f(u1.w)};
  float ep[4] = {bf2f(u2.x), bf2f(u2.y), bf2f(u2.z), bf2f(u2.w)};

  float vals[9];
#pragma unroll
  for (int i = 0; i < 9; i++) vals[i] = 0.f;
#pragma unroll
  for (int j = 0; j < 4; j++) {
    int h = tid * 4 + j;
    vals[0] += eb[j] * eb[j];
    vals[1] += ef[j] * ef[j];
    vals[2] += ep[j] * ep[j];
    vals[3] += eb[j] * ef[j];
    vals[4] += eb[j] * ep[j];
    vals[5] += ef[j] * ep[j];
#pragma unroll
    for (int c = 0; c < 3; c++)
      vals[6 + c] += eb[j] * wgW[(long)h * 3 + c] +
                     ef[j] * wgW[(long)(1024 + h) * 3 + c] +
                     ep[j] * wgW[(long)(2048 + h) * 3 + c];
  }

#pragma unroll
  for (int i = 0; i < 9; i++) {
    float v = vals[i];
    for (int off = 32; off; off >>= 1) v += __shfl_down(v, off);
    vals[i] = v;
  }
  __shared__ float red[4][9];
  if ((tid & 63) == 0) {
#pragma unroll
    for (int i = 0; i < 9; i++) red[tid >> 6][i] = vals[i];
  }
  __syncthreads();
  float tot[9];
#pragma unroll
  for (int i = 0; i < 9; i++)
    tot[i] = red[0][i] + red[1][i] + red[2][i] + red[3][i];

  const float EPSF = 1e-12f;
  float nb = fmaxf(sqrtf(tot[0]), EPSF);
  float nf = fmaxf(sqrtf(tot[1]), EPSF);
  float np_ = fmaxf(sqrtf(tot[2]), EPSF);
  float s01 = tot[3] / (nb * nf);
  float s02 = tot[4] / (nb * np_);
  float s12 = tot[5] / (nf * np_);
  bool k01 = s01 > 0.6f, k02 = s02 > 0.6f, k12 = s12 > 0.6f;
  bool any = k01 | k02 | k12;
  float z0 = k01 ? s01 : -1e9f;
  float z1 = k02 ? s02 : -1e9f;
  float z2 = k12 ? s12 : -1e9f;
  float zm = fmaxf(z0, fmaxf(z1, z2));
  float w0 = __expf(z0 - zm), w1 = __expf(z1 - zm), w2 = __expf(z2 - zm);
  float wsum = w0 + w1 + w2;
  w0 /= wsum; w1 /= wsum; w2 /= wsum;

  float g0 = tot[6] + wgb[0], g1 = tot[7] + wgb[1], g2 = tot[8] + wgb[2];
  float gm = fmaxf(g0, fmaxf(g1, g2));
  float f0 = __expf(g0 - gm), f1 = __expf(g1 - gm), f2 = __expf(g2 - gm);
  float fs = f0 + f1 + f2;
  f0 /= fs; f1 /= fs; f2 /= fs;

  float inb = 1.f / nb, inf_ = 1.f / nf, inp = 1.f / np_;
  ushort4 co, wf;
  uint16_t cov[4], wfv[4];
#pragma unroll
  for (int j = 0; j < 4; j++) {
    float b = eb[j], f = ef[j], p = ep[j];
    float nbv = b * inb, nfv = f * inf_, npv = p * inp;
    float c01 = (nbv * nfv > 0.6f) ? 0.5f * (b + f) : 0.f;
    float c02 = (nbv * npv > 0.6f) ? 0.5f * (b + p) : 0.f;
    float c12 = (nfv * npv > 0.6f) ? 0.5f * (f + p) : 0.f;
    float ws = w0 * c01 + w1 * c02 + w2 * c12;
    float cm = any ? ws : (b + f + p) * (1.f / 3.f);
    float wfs = f0 * b + f1 * f + f2 * p;
    cov[j] = f2bf(cm);
    wfv[j] = f2bf(wfs);
  }
  co.x = cov[0]; co.y = cov[1]; co.z = cov[2]; co.w = cov[3];
  wf.x = wfv[0]; wf.y = wfv[1]; wf.z = wfv[2]; wf.w = wfv[3];
  *(ushort4*)(commonb + base) = co;
  *(ushort4*)(fusedA + (long)row * 2048 + tid * 4) = wf;
}

// ------------------------------- launcher ----------------------------------
extern "C" void kernel_launch(void* const* d_in, const int* in_sizes, int n_in,
                              void* d_out, int out_size, void* d_ws, size_t ws_size,
                              hipStream_t stream) {
  (void)in_sizes; (void)n_in; (void)out_size; (void)ws_size;
  const float* brics = (const float*)d_in[0];
  const float* fg    = (const float*)d_in[1];
  const float* ph    = (const float*)d_in[2];
  const float* bw1 = (const float*)d_in[3];  const float* bb1 = (const float*)d_in[4];
  const float* bw2 = (const float*)d_in[5];  const float* bb2 = (const float*)d_in[6];
  const float* fw1 = (const float*)d_in[7];  const float* fb1 = (const float*)d_in[8];
  const float* fw2 = (const float*)d_in[9];  const float* fb2 = (const float*)d_in[10];
  const float* pw1 = (const float*)d_in[11]; const float* pb1 = (const float*)d_in[12];
  const float* pw2 = (const float*)d_in[13]; const float* pb2 = (const float*)d_in[14];
  const float* wgW = (const float*)d_in[15]; const float* wgb = (const float*)d_in[16];
  const float* enhW = (const float*)d_in[17]; const float* enhb = (const float*)d_in[18];
  const float* fusW = (const float*)d_in[19]; const float* fusb = (const float*)d_in[20];
  float* out = (float*)d_out;

  // ws layout (~170 MB): [EB 96MB][FA 64MB][weights ~10MB]
  uint16_t* EB   = (uint16_t*)d_ws;            // 3 * 16384*1024 bf16
  uint16_t* FA   = EB + 3L * 16384 * 1024;     // 16384*2048
  uint16_t* W1T  = FA + 16384L * 2048;         // 3 * 384*1024
  uint16_t* W2T  = W1T + 3L * 384 * 1024;      // 3 * 1024*320
  uint16_t* ENHT = W2T + 3L * 1024 * 320;      // 1024*1024
  uint16_t* FUST = ENHT + 1024L * 1024;        // 1024*2048
  // d_out doubles as scratch before the final GEMM overwrites it:
  uint16_t* YB   = (uint16_t*)d_out;           // 3 * 16384*384 (36MB <= 64MB)
  uint16_t* COM  = (uint16_t*)d_out;           // 16384*1024 (32MB; after YB dead)

  // weight transposes (f32 [K][N] -> bf16 [Npad][Kpad], zero-padded), batched
  cfe_transpose3_cvt_kernel<<<dim3(32, 12, 3), 256, 0, stream>>>(
      bw1, fw1, pw1, W1T, 384L * 1024, 1024, 300, 1024, 384);
  cfe_transpose3_cvt_kernel<<<dim3(10, 32, 3), 256, 0, stream>>>(
      bw2, fw2, pw2, W2T, 1024L * 320, 300, 1024, 320, 1024);
  cfe_transpose3_cvt_kernel<<<dim3(32, 32, 1), 256, 0, stream>>>(
      enhW, enhW, enhW, ENHT, 0, 1024, 1024, 1024, 1024);
  cfe_transpose3_cvt_kernel<<<dim3(64, 32, 1), 256, 0, stream>>>(
      fusW, fusW, fusW, FUST, 0, 2048, 1024, 2048, 1024);

  // GEMM1: Y = relu(X @ W1 + b1)   M=16384 N=384 K=1024, A = f32 inputs
  cfe_gemm128<0, 1><<<dim3(3, 128, 3), 256, 0, stream>>>(
      brics, fg, ph, 1024, W1T, 384L * 1024, 1024,
      YB, 16384L * 384, 384, 0, bb1, fb1, pb1, 300, nullptr, 1024);

  // GEMM2: E = Y @ W2 + b2         M=16384 N=1024 K=320
  cfe_gemm128<1, 0><<<dim3(8, 128, 3), 256, 0, stream>>>(
      YB, YB + 16384L * 384, YB + 2 * 16384L * 384, 384, W2T, 1024L * 320, 320,
      EB, 16384L * 1024, 1024, 0, bb2, fb2, pb2, 1024, nullptr, 320);

  // pointwise: common (-> d_out region) + weighted_fp_sum (-> FA left half)
  cfe_pointwise_kernel<<<16384, 256, 0, stream>>>(EB, wgW, wgb, COM, FA);

  // enh: FA[:,1024:] = common * sigmoid(common @ enhW + enhb)
  cfe_gemm128<2, 0><<<dim3(8, 128, 1), 256, 0, stream>>>(
      COM, COM, COM, 1024, ENHT, 0, 1024,
      FA, 0, 2048, 1024, enhb, enhb, enhb, 1024, COM, 1024);

  // fused: out = FA @ fusW + fusb   M=16384 N=1024 K=2048
  cfe_gemm128<3, 0><<<dim3(8, 128, 1), 256, 0, stream>>>(
      FA, FA, FA, 2048, FUST, 0, 2048,
      out, 0, 1024, 0, fusb, fusb, fusb, 1024, nullptr, 2048);
}

// Round 4
// 544.613 us; speedup vs baseline: 1.1490x; 1.0445x over previous
//
#include <hip/hip_runtime.h>
#include <stdint.h>

// ---------------------------------------------------------------------------
// CommonFeatureExtractor on MI355X.  Round 4.
// Changes vs round 3:
//  - GEMM1 AF32 staging software-pipelined: next K-tile's float4 loads are
//    issued right after the staging barrier so they overlap the MFMA section
//    (round 3 exposed full load latency every iteration: MfmaUtil 11.7%,
//    HBM 15%, VALU 14% -> latency-bound at 130 us).
//  - f32->bf16 via native (__bf16) casts (v_cvt_pk_bf16_f32) instead of
//    4-op manual RNE: cuts pack/epilogue VALU ~4x.
//  - 4 transpose launches merged into 1 (range-decoded blocks).
// Kept: XCD swizzle (FETCH 266->119 MB on fused GEMM), buffer aliasing
// (ws = [EB 96MB][FA 64MB][weights ~10MB]; d_out hosts YB then COM).
// ---------------------------------------------------------------------------

typedef __attribute__((ext_vector_type(8))) __bf16 bf16x8;
typedef __attribute__((ext_vector_type(8))) short short8;
typedef __attribute__((ext_vector_type(4))) float floatx4;

__device__ __forceinline__ uint16_t f2bf(float f) {
  __bf16 h = (__bf16)f;                      // native RNE cvt on gfx950
  return __builtin_bit_cast(uint16_t, h);
}
__device__ __forceinline__ float bf2f(uint16_t h) {
  union { uint32_t u; float f; } v; v.u = ((uint32_t)h) << 16;
  return v.f;
}
__device__ __forceinline__ short8 pack8(float4 a, float4 b) {
  union { __bf16 h[8]; short8 s; } u;
  u.h[0] = (__bf16)a.x; u.h[1] = (__bf16)a.y; u.h[2] = (__bf16)a.z; u.h[3] = (__bf16)a.w;
  u.h[4] = (__bf16)b.x; u.h[5] = (__bf16)b.y; u.h[6] = (__bf16)b.z; u.h[7] = (__bf16)b.w;
  return u.s;
}
__device__ __forceinline__ void gload16(const void* g, void* l) {
  __builtin_amdgcn_global_load_lds(
      (const __attribute__((address_space(1))) void*)g,
      (__attribute__((address_space(3))) void*)l, 16, 0, 0);
}

// ------------- merged transpose + convert: dst[n][k] = src[k][n] ------------
// Segments: W1T 3x(32x12)=1152 | W2T 3x(10x32)=960 | ENHT 32x32=1024 |
//           FUST 64x32=2048   -> 5184 blocks total.
__global__ void cfe_transpose_all(const float* __restrict__ bw1, const float* __restrict__ fw1,
                                  const float* __restrict__ pw1, const float* __restrict__ bw2,
                                  const float* __restrict__ fw2, const float* __restrict__ pw2,
                                  const float* __restrict__ enhW, const float* __restrict__ fusW,
                                  uint16_t* __restrict__ W1T, uint16_t* __restrict__ W2T,
                                  uint16_t* __restrict__ ENHT, uint16_t* __restrict__ FUST) {
  int bid = blockIdx.x;
  const float* src; uint16_t* dst; int K, N, Kpad, Npad, bx, by;
  if (bid < 1152) {
    int z = bid / 384, t = bid % 384; bx = t % 32; by = t / 32;
    src = (z == 0) ? bw1 : ((z == 1) ? fw1 : pw1); dst = W1T + (long)z * 384 * 1024;
    K = 1024; N = 300; Kpad = 1024; Npad = 384;
  } else if (bid < 2112) {
    bid -= 1152; int z = bid / 320, t = bid % 320; bx = t % 10; by = t / 10;
    src = (z == 0) ? bw2 : ((z == 1) ? fw2 : pw2); dst = W2T + (long)z * 1024 * 320;
    K = 300; N = 1024; Kpad = 320; Npad = 1024;
  } else if (bid < 3136) {
    bid -= 2112; bx = bid % 32; by = bid / 32;
    src = enhW; dst = ENHT; K = 1024; N = 1024; Kpad = 1024; Npad = 1024;
  } else {
    bid -= 3136; bx = bid % 64; by = bid / 64;
    src = fusW; dst = FUST; K = 2048; N = 1024; Kpad = 2048; Npad = 1024;
  }
  __shared__ float tile[32][33];
  const int tx = threadIdx.x & 31;
  const int ty = threadIdx.x >> 5;  // 0..7
  const int k0 = bx * 32;
  const int n0 = by * 32;
#pragma unroll
  for (int i = 0; i < 4; i++) {
    int k = k0 + ty + 8 * i;
    int n = n0 + tx;
    tile[ty + 8 * i][tx] = (k < K && n < N) ? src[(long)k * N + n] : 0.f;
  }
  __syncthreads();
#pragma unroll
  for (int i = 0; i < 4; i++) {
    int n = n0 + ty + 8 * i;
    int k = k0 + tx;
    if (n < Npad && k < Kpad) dst[(long)n * Kpad + k] = f2bf(tile[tx][ty + 8 * i]);
  }
}

// ------------------------------- GEMM 128x128 -------------------------------
// A (z-select among A0/A1/A2): bf16 [M][lda], or f32 when AF32=1 (pipelined
// register staging).  Bt [N][ldb] bf16 (z via sBz).  C per MODE.
// MODE 0: bias+relu -> bf16 ; MODE 1: bias -> bf16 ;
// MODE 2: sigmoid(acc+bias)*common -> bf16 at col offset ; MODE 3: bias -> f32
template <int MODE, int AF32>
__global__ void cfe_gemm128(const void* __restrict__ A0, const void* __restrict__ A1,
                            const void* __restrict__ A2, int lda,
                            const uint16_t* __restrict__ Bt, long sBz, int ldb,
                            void* __restrict__ C, long sCz, int ldc, int colofs,
                            const float* __restrict__ bias0,
                            const float* __restrict__ bias1,
                            const float* __restrict__ bias2, int biasN,
                            const uint16_t* __restrict__ common, int K) {
  const int z = blockIdx.z;
  const void* Av = (z == 0) ? A0 : ((z == 1) ? A1 : A2);
  Bt += (long)z * sBz;
  const float* bias = (z == 0) ? bias0 : ((z == 1) ? bias1 : bias2);

  // XCD-aware swizzle: blocks sharing an A-strip land contiguously on one XCD.
  const int gx = gridDim.x;
  const int lin = blockIdx.y * gx + blockIdx.x;
  const int P = (gx * gridDim.y) >> 3;
  const int v = (lin & 7) * P + (lin >> 3);
  const long bm = (long)(v / gx) * 128;
  const long bn = (long)(v % gx) * 128;

  const int tid = threadIdx.x;
  const int wave = tid >> 6;
  const int lane = tid & 63;
  const int wm = wave >> 1;  // 0..1
  const int wn = wave & 1;

  __shared__ __attribute__((aligned(16))) uint16_t As[128 * 32];
  __shared__ __attribute__((aligned(16))) uint16_t Bs[128 * 32];

  floatx4 acc[4][4];
#pragma unroll
  for (int i = 0; i < 4; i++)
#pragma unroll
    for (int j = 0; j < 4; j++) acc[i][j] = (floatx4){0.f, 0.f, 0.f, 0.f};

  // staging: each wave fills 32 rows of As/Bs; one issue = 16 rows (4 lanes/row)
  const int lrow = lane >> 2;
  const int lcol = (lane & 3) * 8;  // element offset (8 elems/lane)
  const uint16_t* Bp = Bt + (bn + wave * 32 + lrow) * (long)ldb + lcol;
  uint16_t* BsW0 = &Bs[(wave * 32) * 32];
  uint16_t* BsW1 = &Bs[(wave * 32 + 16) * 32];
  // bf16-A path
  const uint16_t* Ap = nullptr;
  uint16_t* AsW0 = &As[(wave * 32) * 32];
  uint16_t* AsW1 = &As[(wave * 32 + 16) * 32];
  // f32-A path
  const float* ApF0 = nullptr;
  const float* ApF1 = nullptr;
  short8* AsF0 = (short8*)&As[(wave * 32 + lrow) * 32 + lcol];
  short8* AsF1 = (short8*)&As[(wave * 32 + 16 + lrow) * 32 + lcol];
  if constexpr (AF32) {
    ApF0 = (const float*)Av + (bm + wave * 32 + lrow) * (long)lda + lcol;
    ApF1 = ApF0 + 16 * (long)lda;
  } else {
    Ap = (const uint16_t*)Av + (bm + wave * 32 + lrow) * (long)lda + lcol;
  }

  const int fr = lane & 15;
  const int fq = lane >> 4;  // 0..3
  const uint16_t* ArBase = &As[(wm * 64 + fr) * 32 + fq * 8];
  const uint16_t* BrBase = &Bs[(wn * 64 + fr) * 32 + fq * 8];

  float4 f0, f1, f2, f3;
  if constexpr (AF32) {  // preload tile 0 into registers
    f0 = *(const float4*)(ApF0);
    f1 = *(const float4*)(ApF0 + 4);
    f2 = *(const float4*)(ApF1);
    f3 = *(const float4*)(ApF1 + 4);
  }

  for (int k0 = 0; k0 < K; k0 += 32) {
    if constexpr (AF32) {
      gload16(Bp + k0, BsW0);
      gload16(Bp + 16 * (long)ldb + k0, BsW1);
      *AsF0 = pack8(f0, f1);   // stage current registers
      *AsF1 = pack8(f2, f3);
    } else {
      gload16(Ap + k0, AsW0);
      gload16(Ap + 16 * (long)lda + k0, AsW1);
      gload16(Bp + k0, BsW0);
      gload16(Bp + 16 * (long)ldb + k0, BsW1);
    }
    __syncthreads();

    if constexpr (AF32) {  // prefetch next tile: overlaps the MFMA section
      if (k0 + 32 < K) {
        f0 = *(const float4*)(ApF0 + k0 + 32);
        f1 = *(const float4*)(ApF0 + k0 + 36);
        f2 = *(const float4*)(ApF1 + k0 + 32);
        f3 = *(const float4*)(ApF1 + k0 + 36);
      }
    }

    short8 a[4], b[4];
#pragma unroll
    for (int mi = 0; mi < 4; mi++) a[mi] = *(const short8*)(ArBase + mi * 16 * 32);
#pragma unroll
    for (int ni = 0; ni < 4; ni++) b[ni] = *(const short8*)(BrBase + ni * 16 * 32);
#pragma unroll
    for (int mi = 0; mi < 4; mi++)
#pragma unroll
      for (int ni = 0; ni < 4; ni++)
        acc[mi][ni] = __builtin_amdgcn_mfma_f32_16x16x32_bf16(
            __builtin_bit_cast(bf16x8, a[mi]), __builtin_bit_cast(bf16x8, b[ni]),
            acc[mi][ni], 0, 0, 0);
    __syncthreads();
  }

  // epilogue: D[row=fq*4+r][col=fr] per 16x16 tile
#pragma unroll
  for (int mi = 0; mi < 4; mi++) {
    long row = bm + wm * 64 + mi * 16 + fq * 4;
#pragma unroll
    for (int ni = 0; ni < 4; ni++) {
      long col = bn + wn * 64 + ni * 16 + fr;
      float bv = (col < biasN) ? bias[col] : 0.f;
#pragma unroll
      for (int r = 0; r < 4; r++) {
        float vv = acc[mi][ni][r] + bv;
        long idx = (row + r) * (long)ldc + colofs + col;
        if constexpr (MODE == 0) {
          ((uint16_t*)C)[(long)z * sCz + idx] = f2bf(fmaxf(vv, 0.f));
        } else if constexpr (MODE == 1) {
          ((uint16_t*)C)[(long)z * sCz + idx] = f2bf(vv);
        } else if constexpr (MODE == 2) {
          float c = bf2f(common[(row + r) * 1024 + col]);
          float s = 1.f / (1.f + __expf(-vv));
          ((uint16_t*)C)[idx] = f2bf(c * s);
        } else {
          ((float*)C)[idx] = vv;
        }
      }
    }
  }
}

// ------------------------------- pointwise ---------------------------------
// One block per row. E = [eb|ef|ep] bf16, each 16384x1024, contiguous.
__global__ void cfe_pointwise_kernel(const uint16_t* __restrict__ E,
                                     const float* __restrict__ wgW,
                                     const float* __restrict__ wgb,
                                     uint16_t* __restrict__ commonb,
                                     uint16_t* __restrict__ fusedA) {
  const int row = blockIdx.x;
  const int tid = threadIdx.x;
  const long ES = 16384L * 1024;
  const long base = (long)row * 1024 + tid * 4;

  ushort4 u0 = *(const ushort4*)(E + base);
  ushort4 u1 = *(const ushort4*)(E + ES + base);
  ushort4 u2 = *(const ushort4*)(E + 2 * ES + base);
  float eb[4] = {bf2f(u0.x), bf2f(u0.y), bf2f(u0.z), bf2f(u0.w)};
  float ef[4] = {bf2f(u1.x), bf2f(u1.y), bf2f(u1.z), bf2f(u1.w)};
  float ep[4] = {bf2f(u2.x), bf2f(u2.y), bf2f(u2.z), bf2f(u2.w)};

  float vals[9];
#pragma unroll
  for (int i = 0; i < 9; i++) vals[i] = 0.f;
#pragma unroll
  for (int j = 0; j < 4; j++) {
    int h = tid * 4 + j;
    vals[0] += eb[j] * eb[j];
    vals[1] += ef[j] * ef[j];
    vals[2] += ep[j] * ep[j];
    vals[3] += eb[j] * ef[j];
    vals[4] += eb[j] * ep[j];
    vals[5] += ef[j] * ep[j];
#pragma unroll
    for (int c = 0; c < 3; c++)
      vals[6 + c] += eb[j] * wgW[(long)h * 3 + c] +
                     ef[j] * wgW[(long)(1024 + h) * 3 + c] +
                     ep[j] * wgW[(long)(2048 + h) * 3 + c];
  }

#pragma unroll
  for (int i = 0; i < 9; i++) {
    float v = vals[i];
    for (int off = 32; off; off >>= 1) v += __shfl_down(v, off);
    vals[i] = v;
  }
  __shared__ float red[4][9];
  if ((tid & 63) == 0) {
#pragma unroll
    for (int i = 0; i < 9; i++) red[tid >> 6][i] = vals[i];
  }
  __syncthreads();
  float tot[9];
#pragma unroll
  for (int i = 0; i < 9; i++)
    tot[i] = red[0][i] + red[1][i] + red[2][i] + red[3][i];

  const float EPSF = 1e-12f;
  float nb = fmaxf(sqrtf(tot[0]), EPSF);
  float nf = fmaxf(sqrtf(tot[1]), EPSF);
  float np_ = fmaxf(sqrtf(tot[2]), EPSF);
  float s01 = tot[3] / (nb * nf);
  float s02 = tot[4] / (nb * np_);
  float s12 = tot[5] / (nf * np_);
  bool k01 = s01 > 0.6f, k02 = s02 > 0.6f, k12 = s12 > 0.6f;
  bool any = k01 | k02 | k12;
  float z0 = k01 ? s01 : -1e9f;
  float z1 = k02 ? s02 : -1e9f;
  float z2 = k12 ? s12 : -1e9f;
  float zm = fmaxf(z0, fmaxf(z1, z2));
  float w0 = __expf(z0 - zm), w1 = __expf(z1 - zm), w2 = __expf(z2 - zm);
  float wsum = w0 + w1 + w2;
  w0 /= wsum; w1 /= wsum; w2 /= wsum;

  float g0 = tot[6] + wgb[0], g1 = tot[7] + wgb[1], g2 = tot[8] + wgb[2];
  float gm = fmaxf(g0, fmaxf(g1, g2));
  float f0 = __expf(g0 - gm), f1 = __expf(g1 - gm), f2 = __expf(g2 - gm);
  float fs = f0 + f1 + f2;
  f0 /= fs; f1 /= fs; f2 /= fs;

  float inb = 1.f / nb, inf_ = 1.f / nf, inp = 1.f / np_;
  ushort4 co, wf;
  uint16_t cov[4], wfv[4];
#pragma unroll
  for (int j = 0; j < 4; j++) {
    float b = eb[j], f = ef[j], p = ep[j];
    float nbv = b * inb, nfv = f * inf_, npv = p * inp;
    float c01 = (nbv * nfv > 0.6f) ? 0.5f * (b + f) : 0.f;
    float c02 = (nbv * npv > 0.6f) ? 0.5f * (b + p) : 0.f;
    float c12 = (nfv * npv > 0.6f) ? 0.5f * (f + p) : 0.f;
    float ws = w0 * c01 + w1 * c02 + w2 * c12;
    float cm = any ? ws : (b + f + p) * (1.f / 3.f);
    float wfs = f0 * b + f1 * f + f2 * p;
    cov[j] = f2bf(cm);
    wfv[j] = f2bf(wfs);
  }
  co.x = cov[0]; co.y = cov[1]; co.z = cov[2]; co.w = cov[3];
  wf.x = wfv[0]; wf.y = wfv[1]; wf.z = wfv[2]; wf.w = wfv[3];
  *(ushort4*)(commonb + base) = co;
  *(ushort4*)(fusedA + (long)row * 2048 + tid * 4) = wf;
}

// ------------------------------- launcher ----------------------------------
extern "C" void kernel_launch(void* const* d_in, const int* in_sizes, int n_in,
                              void* d_out, int out_size, void* d_ws, size_t ws_size,
                              hipStream_t stream) {
  (void)in_sizes; (void)n_in; (void)out_size; (void)ws_size;
  const float* brics = (const float*)d_in[0];
  const float* fg    = (const float*)d_in[1];
  const float* ph    = (const float*)d_in[2];
  const float* bw1 = (const float*)d_in[3];  const float* bb1 = (const float*)d_in[4];
  const float* bw2 = (const float*)d_in[5];  const float* bb2 = (const float*)d_in[6];
  const float* fw1 = (const float*)d_in[7];  const float* fb1 = (const float*)d_in[8];
  const float* fw2 = (const float*)d_in[9];  const float* fb2 = (const float*)d_in[10];
  const float* pw1 = (const float*)d_in[11]; const float* pb1 = (const float*)d_in[12];
  const float* pw2 = (const float*)d_in[13]; const float* pb2 = (const float*)d_in[14];
  const float* wgW = (const float*)d_in[15]; const float* wgb = (const float*)d_in[16];
  const float* enhW = (const float*)d_in[17]; const float* enhb = (const float*)d_in[18];
  const float* fusW = (const float*)d_in[19]; const float* fusb = (const float*)d_in[20];
  float* out = (float*)d_out;

  // ws layout (~170 MB): [EB 96MB][FA 64MB][weights ~10MB]
  uint16_t* EB   = (uint16_t*)d_ws;            // 3 * 16384*1024 bf16
  uint16_t* FA   = EB + 3L * 16384 * 1024;     // 16384*2048
  uint16_t* W1T  = FA + 16384L * 2048;         // 3 * 384*1024
  uint16_t* W2T  = W1T + 3L * 384 * 1024;      // 3 * 1024*320
  uint16_t* ENHT = W2T + 3L * 1024 * 320;      // 1024*1024
  uint16_t* FUST = ENHT + 1024L * 1024;        // 1024*2048
  // d_out doubles as scratch before the final GEMM overwrites it:
  uint16_t* YB   = (uint16_t*)d_out;           // 3 * 16384*384 (36MB <= 64MB)
  uint16_t* COM  = (uint16_t*)d_out;           // 16384*1024 (32MB; after YB dead)

  // all weight transposes in one launch
  cfe_transpose_all<<<5184, 256, 0, stream>>>(
      bw1, fw1, pw1, bw2, fw2, pw2, enhW, fusW, W1T, W2T, ENHT, FUST);

  // GEMM1: Y = relu(X @ W1 + b1)   M=16384 N=384 K=1024, A = f32 inputs
  cfe_gemm128<0, 1><<<dim3(3, 128, 3), 256, 0, stream>>>(
      brics, fg, ph, 1024, W1T, 384L * 1024, 1024,
      YB, 16384L * 384, 384, 0, bb1, fb1, pb1, 300, nullptr, 1024);

  // GEMM2: E = Y @ W2 + b2         M=16384 N=1024 K=320
  cfe_gemm128<1, 0><<<dim3(8, 128, 3), 256, 0, stream>>>(
      YB, YB + 16384L * 384, YB + 2 * 16384L * 384, 384, W2T, 1024L * 320, 320,
      EB, 16384L * 1024, 1024, 0, bb2, fb2, pb2, 1024, nullptr, 320);

  // pointwise: common (-> d_out region) + weighted_fp_sum (-> FA left half)
  cfe_pointwise_kernel<<<16384, 256, 0, stream>>>(EB, wgW, wgb, COM, FA);

  // enh: FA[:,1024:] = common * sigmoid(common @ enhW + enhb)
  cfe_gemm128<2, 0><<<dim3(8, 128, 1), 256, 0, stream>>>(
      COM, COM, COM, 1024, ENHT, 0, 1024,
      FA, 0, 2048, 1024, enhb, enhb, enhb, 1024, COM, 1024);

  // fused: out = FA @ fusW + fusb   M=16384 N=1024 K=2048
  cfe_gemm128<3, 0><<<dim3(8, 128, 1), 256, 0, stream>>>(
      FA, FA, FA, 2048, FUST, 0, 2048,
      out, 0, 1024, 0, fusb, fusb, fusb, 1024, nullptr, 2048);
}